// Round 11
// baseline (126.927 us; speedup 1.0000x reference)
//
#include <hip/hip_runtime.h>
#include <hip/hip_bf16.h>

#define B_   2
#define S_   2048
#define E_   1024
#define H_   16
#define HD_  64
#define E3_  3072
#define M_   4096   // B*S
#define QKS  2048   // stride of QK buffer
#define QSC  0.1803368801111f   // 0.125 * log2(e): Q pre-scale, exp2 domain

using short8 = __attribute__((ext_vector_type(8))) short;
using f32x4  = __attribute__((ext_vector_type(4))) float;

__device__ __forceinline__ unsigned short f2bf(float f) {
  union { float f; unsigned v; } t; t.f = f;
  unsigned r = t.v + 0x7FFFu + ((t.v >> 16) & 1u);  // RNE
  return (unsigned short)(r >> 16);
}

__device__ __forceinline__ float exp2_fast(float x) {
  float r;
  asm("v_exp_f32 %0, %1" : "=v"(r) : "v"(x));
  return r;
}

__device__ __forceinline__ void gload16(const void* g, void* l) {
  __builtin_amdgcn_global_load_lds(
      (const __attribute__((address_space(1))) unsigned int*)g,
      (__attribute__((address_space(3))) unsigned int*)l, 16, 0, 0);
}

// ---------------- f32 -> bf16 convert ----------------
__global__ void cvt_f32_bf16(const float* __restrict__ in,
                             unsigned short* __restrict__ out, int n) {
  int i = (blockIdx.x * blockDim.x + threadIdx.x) * 4;
  if (i < n) {
    float4 v = *(const float4*)(in + i);
    ushort4 o;
    o.x = f2bf(v.x); o.y = f2bf(v.y); o.z = f2bf(v.z); o.w = f2bf(v.w);
    *(ushort4*)(out + i) = o;
  }
}

// ---------------- W [K][N] f32 -> WT [N][K] bf16 ----------------
__global__ void transpose_bf16(const float* __restrict__ W,
                               unsigned short* __restrict__ WT, int K, int N) {
  __shared__ float tile[32][33];
  int bn = blockIdx.x * 32, bk = blockIdx.y * 32;
  int tx = threadIdx.x & 31, ty = threadIdx.x >> 5;  // 32 x 8
  #pragma unroll
  for (int i = 0; i < 32; i += 8)
    tile[ty + i][tx] = W[(size_t)(bk + ty + i) * N + bn + tx];
  __syncthreads();
  #pragma unroll
  for (int i = 0; i < 32; i += 8)
    WT[(size_t)(bn + ty + i) * K + bk + tx] = f2bf(tile[tx][ty + i]);
}

// ------- QKV GEMM: 256x128 tile, 512 thr (8 waves 4Mx2N), BK=64, swizzled ----
// A=Xb [M][1024] bf16, BT=WaT [3072][1024] bf16. Epilogue: Q cols (<1024)
// pre-scaled by QSC -> QK; K cols -> QK; V cols (>=2048) transposed -> Vt.
__global__ __launch_bounds__(512) void gemm_qkv256(
    const unsigned short* __restrict__ A,
    const unsigned short* __restrict__ BT,
    const float* __restrict__ bias,
    unsigned short* __restrict__ Cbf,
    unsigned short* __restrict__ Vt) {
  __shared__ __align__(16) unsigned short As[256 * 64];
  __shared__ __align__(16) unsigned short Bs[128 * 64];
  const int t = threadIdx.x;
  const int lane = t & 63, w = t >> 6;
  const int wr = w >> 1, wc = w & 1;                 // 4M x 2N wave grid
  const int m0 = blockIdx.y * 256, n0 = blockIdx.x * 128;
  const int lrow = lane & 15, lkg = lane >> 4;
  const int srow = t >> 3;                           // 0..63
  const int sc8  = (t & 7) * 8;
  const int sgc  = sc8 ^ ((srow & 7) << 3);          // swizzled source col
  const int K = E_;

  f32x4 acc[4][4];
  const f32x4 z = {0.f, 0.f, 0.f, 0.f};
  #pragma unroll
  for (int i = 0; i < 4; ++i)
    #pragma unroll
    for (int j = 0; j < 4; ++j) acc[i][j] = z;

  for (int k0 = 0; k0 < K; k0 += 64) {
    __syncthreads();
    #pragma unroll
    for (int p = 0; p < 4; ++p) {
      const int r = srow + 64 * p;
      gload16(A + (size_t)(m0 + r) * K + k0 + sgc, &As[r * 64 + sc8]);
    }
    #pragma unroll
    for (int p = 0; p < 2; ++p) {
      const int r = srow + 64 * p;
      gload16(BT + (size_t)(n0 + r) * K + k0 + sgc, &Bs[r * 64 + sc8]);
    }
    __syncthreads();

    short8 af[4][2], bf[4][2];
    #pragma unroll
    for (int m = 0; m < 4; ++m) {
      const int row = wr * 64 + m * 16 + lrow;
      const int base = row * 64, sw = (row & 7) << 3;
      af[m][0] = *(const short8*)&As[base + ((lkg * 8) ^ sw)];
      af[m][1] = *(const short8*)&As[base + ((32 + lkg * 8) ^ sw)];
    }
    #pragma unroll
    for (int n = 0; n < 4; ++n) {
      const int row = wc * 64 + n * 16 + lrow;
      const int base = row * 64, sw = (row & 7) << 3;
      bf[n][0] = *(const short8*)&Bs[base + ((lkg * 8) ^ sw)];
      bf[n][1] = *(const short8*)&Bs[base + ((32 + lkg * 8) ^ sw)];
    }
    #pragma unroll
    for (int m = 0; m < 4; ++m)
      #pragma unroll
      for (int n = 0; n < 4; ++n) {
        acc[m][n] = __builtin_amdgcn_mfma_f32_16x16x32_bf16(af[m][0], bf[n][0],
                                                            acc[m][n], 0, 0, 0);
        acc[m][n] = __builtin_amdgcn_mfma_f32_16x16x32_bf16(af[m][1], bf[n][1],
                                                            acc[m][n], 0, 0, 0);
      }
  }

  const int r0 = (lane >> 4) * 4, c0 = lane & 15;
  #pragma unroll
  for (int m = 0; m < 4; ++m) {
    #pragma unroll
    for (int n = 0; n < 4; ++n) {
      const int row = m0 + wr * 64 + m * 16 + r0;
      const int col = n0 + wc * 64 + n * 16 + c0;
      const float bv = bias[col];
      if (col < 2 * E_) {
        const float sc = (col < E_) ? QSC : 1.0f;    // uniform per 16-col block
        #pragma unroll
        for (int r = 0; r < 4; ++r)
          Cbf[(size_t)(row + r) * QKS + col] = f2bf((acc[m][n][r] + bv) * sc);
      } else {
        const int hd = col - 2 * E_;
        ushort4 o;
        o.x = f2bf(acc[m][n][0] + bv);
        o.y = f2bf(acc[m][n][1] + bv);
        o.z = f2bf(acc[m][n][2] + bv);
        o.w = f2bf(acc[m][n][3] + bv);
        *(ushort4*)&Vt[(((size_t)(row >> 11) * H_ + (hd >> 6)) * HD_ +
                        (hd & 63)) * (size_t)S_ + (row & 2047)] = o;
      }
    }
  }
}

// ------- proj GEMM: 128x128 bf16 MFMA, BK=64, XOR-swizzled LDS, f32 out -----
__global__ __launch_bounds__(256) void gemm_proj(
    const unsigned short* __restrict__ A,
    const unsigned short* __restrict__ BT,
    const float* __restrict__ bias,
    float* __restrict__ Cf, int M, int N, int K) {
  __shared__ __align__(16) unsigned short As[128 * 64];
  __shared__ __align__(16) unsigned short Bs[128 * 64];
  const int t = threadIdx.x;
  const int lane = t & 63, w = t >> 6;
  const int wr = w >> 1, wc = w & 1;
  const int m0 = blockIdx.y * 128, n0 = blockIdx.x * 128;
  const int lrow = lane & 15, lkg = lane >> 4;
  const int srow = t >> 3;            // 0..31 (+32p)
  const int sc8  = (t & 7) * 8;
  const int sgc  = sc8 ^ (((t >> 3) & 7) << 3);

  f32x4 acc[4][4];
  const f32x4 z = {0.f, 0.f, 0.f, 0.f};
  #pragma unroll
  for (int i = 0; i < 4; ++i)
    #pragma unroll
    for (int j = 0; j < 4; ++j) acc[i][j] = z;

  for (int k0 = 0; k0 < K; k0 += 64) {
    __syncthreads();
    #pragma unroll
    for (int p = 0; p < 4; ++p) {
      const int r = srow + 32 * p;
      gload16(A  + (size_t)(m0 + r) * K + k0 + sgc, &As[r * 64 + sc8]);
      gload16(BT + (size_t)(n0 + r) * K + k0 + sgc, &Bs[r * 64 + sc8]);
    }
    __syncthreads();

    short8 af[4][2], bf[4][2];
    #pragma unroll
    for (int m = 0; m < 4; ++m) {
      const int row = wr * 64 + m * 16 + lrow;
      const int base = row * 64, sw = (row & 7) << 3;
      af[m][0] = *(const short8*)&As[base + ((lkg * 8) ^ sw)];
      af[m][1] = *(const short8*)&As[base + ((32 + lkg * 8) ^ sw)];
    }
    #pragma unroll
    for (int n = 0; n < 4; ++n) {
      const int row = wc * 64 + n * 16 + lrow;
      const int base = row * 64, sw = (row & 7) << 3;
      bf[n][0] = *(const short8*)&Bs[base + ((lkg * 8) ^ sw)];
      bf[n][1] = *(const short8*)&Bs[base + ((32 + lkg * 8) ^ sw)];
    }
    #pragma unroll
    for (int m = 0; m < 4; ++m)
      #pragma unroll
      for (int n = 0; n < 4; ++n) {
        acc[m][n] = __builtin_amdgcn_mfma_f32_16x16x32_bf16(af[m][0], bf[n][0],
                                                            acc[m][n], 0, 0, 0);
        acc[m][n] = __builtin_amdgcn_mfma_f32_16x16x32_bf16(af[m][1], bf[n][1],
                                                            acc[m][n], 0, 0, 0);
      }
  }

  const int r0 = (lane >> 4) * 4, c0 = lane & 15;
  #pragma unroll
  for (int m = 0; m < 4; ++m) {
    #pragma unroll
    for (int n = 0; n < 4; ++n) {
      const int row = m0 + wr * 64 + m * 16 + r0;
      const int col = n0 + wc * 64 + n * 16 + c0;
      const float bv = bias[col];
      #pragma unroll
      for (int r = 0; r < 4; ++r)
        Cf[(size_t)(row + r) * N + col] = acc[m][n][r] + bv;
    }
  }
}

// ---------------- flash attention (causal), QBLK=64, KVBLK=64 ----------------
// Swapped-QK^T; scores in exp2 domain (Q pre-scaled by 0.125*log2e).
// Fixed-reference softmax (no running max) => linear in kv-range; qt 24..31
// split into two kv-chunks writing f32 partials, combined by attn_combine.
__global__ __launch_bounds__(256) void flash_attn(
    const unsigned short* __restrict__ qk,
    const unsigned short* __restrict__ Vt,
    unsigned short* __restrict__ aout,
    float* __restrict__ Opart,           // [256][2][64][64]
    float* __restrict__ Lpart) {         // [256][2][64]
  __shared__ __align__(16) unsigned short Ks[2][64 * 64];   // [k][d], swizzled
  __shared__ __align__(16) unsigned short Vs[2][64 * 64];   // [d][k], swizzled
  __shared__ __align__(16) unsigned short Ps[4][16 * 64];   // per-wave P[q][k]

  const int t = threadIdx.x, lane = t & 63, w = t >> 6;
  const int bh = blockIdx.x;
  const int yy = blockIdx.y;            // 0..39, dispatch order = work order
  int qt, lo, hi, part = 0;
  bool split = false;
  if (yy < 8) {                         // longest singles first: len 24..17
    qt = 23 - yy; lo = 0; hi = qt + 1;
  } else if (yy < 24) {                 // split chunks: len ~16..12
    const int idx = yy - 8;
    qt = 31 - (idx >> 1); part = idx & 1;
    const int mid = (qt + 2) >> 1;
    lo = part ? mid : 0; hi = part ? qt + 1 : mid;
    split = true;
  } else {                              // short singles: len 16..1
    qt = 39 - yy; lo = 0; hi = qt + 1;
  }
  const int b = bh >> 4, h = bh & 15;
  const int lq = lane & 15;
  const int g  = lane >> 4;
  const int lk8 = g * 8;
  const int swzq = (lq & 7) << 3;
  const size_t basebs = (size_t)b * S_;
  const f32x4 z = {0.f, 0.f, 0.f, 0.f};

  short8 qf[2];
  {
    const int qrow = qt * 64 + w * 16 + lq;
    const unsigned short* qp = qk + (basebs + qrow) * QKS + h * HD_;
    qf[0] = *(const short8*)(qp + lk8);
    qf[1] = *(const short8*)(qp + 32 + lk8);
  }

  float l_q = 0.f;
  f32x4 o_acc[4];
  #pragma unroll
  for (int n = 0; n < 4; ++n) o_acc[n] = z;

  const int sr = t >> 3, scc = (t & 7) * 8;
  const unsigned short* kp0 =
      qk + (basebs + sr) * QKS + E_ + h * HD_ + (scc ^ ((sr & 7) << 3));
  const unsigned short* kp1 = kp0 + 32 * QKS;
  const unsigned short* vp0 =
      Vt + ((size_t)bh * HD_ + sr) * S_ + (scc ^ ((sr & 7) << 3));
  const unsigned short* vp1 = vp0 + 32 * S_;

  auto stage = [&](int buf, int kt) {
    const size_t koff = (size_t)kt * 64 * QKS;
    const size_t voff = (size_t)kt * 64;
    gload16(kp0 + koff, &Ks[buf][t * 8]);
    gload16(kp1 + koff, &Ks[buf][t * 8 + 2048]);
    gload16(vp0 + voff, &Vs[buf][t * 8]);
    gload16(vp1 + voff, &Vs[buf][t * 8 + 2048]);
  };

  stage(0, lo);
  __syncthreads();
  int cur = 0;

  for (int kt = lo; kt < hi; ++kt) {
    if (kt + 1 < hi) stage(cur ^ 1, kt + 1);

    f32x4 st[4];
    __builtin_amdgcn_s_setprio(1);
    #pragma unroll
    for (int f = 0; f < 4; ++f) {
      const int rowb = (f * 16 + lq) * 64;
      short8 kf0 = *(const short8*)&Ks[cur][rowb + (lk8 ^ swzq)];
      short8 kf1 = *(const short8*)&Ks[cur][rowb + ((lk8 + 32) ^ swzq)];
      st[f] = __builtin_amdgcn_mfma_f32_16x16x32_bf16(kf0, qf[0], z, 0, 0, 0);
      st[f] = __builtin_amdgcn_mfma_f32_16x16x32_bf16(kf1, qf[1], st[f], 0, 0, 0);
    }
    __builtin_amdgcn_s_setprio(0);

    if (kt == qt) {
      const int qcol = w * 16 + lq;
      #pragma unroll
      for (int f = 0; f < 4; ++f)
        #pragma unroll
        for (int r = 0; r < 4; ++r)
          if (16 * f + 4 * g + r > qcol) st[f][r] = -1e30f;
    }

    unsigned pw[4][2];
    #pragma unroll
    for (int f = 0; f < 4; ++f) {
      float p0 = exp2_fast(st[f][0]);
      float p1 = exp2_fast(st[f][1]);
      float p2 = exp2_fast(st[f][2]);
      float p3 = exp2_fast(st[f][3]);
      l_q += (p0 + p1) + (p2 + p3);
      asm("v_cvt_pk_bf16_f32 %0, %1, %2" : "=v"(pw[f][0]) : "v"(p0), "v"(p1));
      asm("v_cvt_pk_bf16_f32 %0, %1, %2" : "=v"(pw[f][1]) : "v"(p2), "v"(p3));
    }

    {
      unsigned short* pr = &Ps[w][lq * 64];
      #pragma unroll
      for (int f = 0; f < 4; ++f) {
        *(unsigned*)&pr[(16 * f + 4 * g) ^ swzq]       = pw[f][0];
        *(unsigned*)&pr[((16 * f + 4 * g + 2) ^ swzq)] = pw[f][1];
      }
    }

    short8 pa0 = *(const short8*)&Ps[w][lq * 64 + (lk8 ^ swzq)];
    short8 pa1 = *(const short8*)&Ps[w][lq * 64 + ((lk8 + 32) ^ swzq)];
    __builtin_amdgcn_s_setprio(1);
    #pragma unroll
    for (int n = 0; n < 4; ++n) {
      const int rowb = (n * 16 + lq) * 64;
      short8 vb0 = *(const short8*)&Vs[cur][rowb + (lk8 ^ swzq)];
      short8 vb1 = *(const short8*)&Vs[cur][rowb + ((lk8 + 32) ^ swzq)];
      o_acc[n] = __builtin_amdgcn_mfma_f32_16x16x32_bf16(pa0, vb0, o_acc[n], 0, 0, 0);
      o_acc[n] = __builtin_amdgcn_mfma_f32_16x16x32_bf16(pa1, vb1, o_acc[n], 0, 0, 0);
    }
    __builtin_amdgcn_s_setprio(0);

    __syncthreads();
    cur ^= 1;
  }

  l_q += __shfl_xor(l_q, 16);
  l_q += __shfl_xor(l_q, 32);

  if (!split) {
    const int qbase = qt * 64 + w * 16 + 4 * g;
    #pragma unroll
    for (int r = 0; r < 4; ++r) {
      const float lr = __shfl(l_q, 4 * g + r);
      const float inv = 1.0f / lr;
      const int row = qbase + r;
      #pragma unroll
      for (int n = 0; n < 4; ++n)
        aout[(basebs + row) * E_ + h * HD_ + n * 16 + lq] =
            f2bf(o_acc[n][r] * inv);
    }
  } else {
    const int sidx = (bh << 3) | (qt - 24);
    float* Ob = Opart + ((size_t)(sidx * 2 + part) << 12);  // 64*64
    #pragma unroll
    for (int r = 0; r < 4; ++r) {
      const int qrow = w * 16 + 4 * g + r;
      #pragma unroll
      for (int n = 0; n < 4; ++n)
        Ob[qrow * 64 + n * 16 + lq] = o_acc[n][r];
    }
    if (g == 0)
      Lpart[(sidx * 2 + part) * 64 + w * 16 + lq] = l_q;
  }
}

// ---------------- combine partials for split row-blocks ----------------
__global__ __launch_bounds__(256) void attn_combine(
    const float* __restrict__ Opart, const float* __restrict__ Lpart,
    unsigned short* __restrict__ aout) {
  const int s = blockIdx.x;            // 0..255
  const int bh = s >> 3, qt = 24 + (s & 7);
  const int b = bh >> 4, h = bh & 15;
  const int t = threadIdx.x;
  const int q = t >> 2;                // 0..63
  const int d0 = (t & 3) * 16;
  const float l = Lpart[(s * 2 + 0) * 64 + q] + Lpart[(s * 2 + 1) * 64 + q];
  const float inv = 1.0f / l;
  const float* p0 = Opart + ((size_t)(s * 2 + 0) << 12) + q * 64 + d0;
  const float* p1 = Opart + ((size_t)(s * 2 + 1) << 12) + q * 64 + d0;
  unsigned short* dst =
      aout + ((size_t)b * S_ + qt * 64 + q) * E_ + h * HD_ + d0;
  #pragma unroll
  for (int i = 0; i < 16; ++i)
    dst[i] = f2bf((p0[i] + p1[i]) * inv);
}

extern "C" void kernel_launch(void* const* d_in, const int* in_sizes, int n_in,
                              void* d_out, int out_size, void* d_ws, size_t ws_size,
                              hipStream_t stream) {
  const float* X  = (const float*)d_in[0];
  const float* Wa = (const float*)d_in[1];
  const float* ba = (const float*)d_in[2];
  const float* Wp = (const float*)d_in[3];
  const float* bp = (const float*)d_in[4];
  float* out = (float*)d_out;

  char* ws = (char*)d_ws;
  unsigned short* Xb  = (unsigned short*)ws; ws += (size_t)M_ * E_ * 2;    // 8 MB
  unsigned short* WaT = (unsigned short*)ws; ws += (size_t)E3_ * E_ * 2;   // 6 MB
  unsigned short* WpT = (unsigned short*)ws; ws += (size_t)E_ * E_ * 2;    // 2 MB
  unsigned short* QK  = (unsigned short*)ws; ws += (size_t)M_ * QKS * 2;   // 16 MB
  unsigned short* Vt  = (unsigned short*)ws; ws += (size_t)M_ * E_ * 2;    // 8 MB
  unsigned short* AO  = (unsigned short*)ws; ws += (size_t)M_ * E_ * 2;    // 8 MB
  float* Opart = (float*)ws; ws += (size_t)256 * 2 * 64 * 64 * 4;          // 8 MB
  float* Lpart = (float*)ws; ws += (size_t)256 * 2 * 64 * 4;               // 128 KB

  cvt_f32_bf16<<<(M_ * E_ / 4 + 255) / 256, 256, 0, stream>>>(X, Xb, M_ * E_);
  transpose_bf16<<<dim3(E3_ / 32, E_ / 32), 256, 0, stream>>>(Wa, WaT, E_, E3_);
  transpose_bf16<<<dim3(E_ / 32, E_ / 32), 256, 0, stream>>>(Wp, WpT, E_, E_);
  gemm_qkv256<<<dim3(E3_ / 128, M_ / 256), 512, 0, stream>>>(
      Xb, WaT, ba, QK, Vt);
  flash_attn<<<dim3(B_ * H_, 40), 256, 0, stream>>>(QK, Vt, AO, Opart, Lpart);
  attn_combine<<<256, 256, 0, stream>>>(Opart, Lpart, AO);
  gemm_proj<<<dim3(E_ / 128, M_ / 128), 256, 0, stream>>>(
      AO, WpT, bp, out, M_, E_, E_);
}

// Round 12
// 106.340 us; speedup vs baseline: 1.1936x; 1.1936x over previous
//
#include <hip/hip_runtime.h>
#include <hip/hip_bf16.h>

#define B_   2
#define S_   2048
#define E_   1024
#define H_   16
#define HD_  64
#define E3_  3072
#define M_   4096   // B*S
#define QKS  2048   // stride of QK buffer
#define QSC  0.1803368801111f   // 0.125 * log2(e): Q pre-scale, exp2 domain

using short8 = __attribute__((ext_vector_type(8))) short;
using f32x4  = __attribute__((ext_vector_type(4))) float;

__device__ __forceinline__ unsigned short f2bf(float f) {
  union { float f; unsigned v; } t; t.f = f;
  unsigned r = t.v + 0x7FFFu + ((t.v >> 16) & 1u);  // RNE
  return (unsigned short)(r >> 16);
}

__device__ __forceinline__ float exp2_fast(float x) {
  float r;
  asm("v_exp_f32 %0, %1" : "=v"(r) : "v"(x));
  return r;
}

__device__ __forceinline__ void gload16(const void* g, void* l) {
  __builtin_amdgcn_global_load_lds(
      (const __attribute__((address_space(1))) unsigned int*)g,
      (__attribute__((address_space(3))) unsigned int*)l, 16, 0, 0);
}

// ---- prep: X f32->bf16 + both weight transposes, one launch ----
// blocks [0,4096): cvt X; [4096,7168): transpose Wa; [7168,8192): transpose Wp
__global__ __launch_bounds__(256) void prep(
    const float* __restrict__ X, const float* __restrict__ Wa,
    const float* __restrict__ Wp,
    unsigned short* __restrict__ Xb, unsigned short* __restrict__ WaT,
    unsigned short* __restrict__ WpT) {
  __shared__ float tile[32][33];
  const int id = blockIdx.x;
  if (id < 4096) {
    const int i = (id * 256 + threadIdx.x) * 4;
    float4 v = *(const float4*)(X + i);
    ushort4 o;
    o.x = f2bf(v.x); o.y = f2bf(v.y); o.z = f2bf(v.z); o.w = f2bf(v.w);
    *(ushort4*)(Xb + i) = o;
  } else {
    const float* W; unsigned short* WT; int N, bn, bk;
    if (id < 7168) {
      W = Wa; WT = WaT; N = E3_;
      const int j = id - 4096; bn = (j % 96) * 32; bk = (j / 96) * 32;
    } else {
      W = Wp; WT = WpT; N = E_;
      const int j = id - 7168; bn = (j & 31) * 32; bk = (j >> 5) * 32;
    }
    const int tx = threadIdx.x & 31, ty = threadIdx.x >> 5;  // 32 x 8
    #pragma unroll
    for (int i2 = 0; i2 < 32; i2 += 8)
      tile[ty + i2][tx] = W[(size_t)(bk + ty + i2) * N + bn + tx];
    __syncthreads();
    #pragma unroll
    for (int i2 = 0; i2 < 32; i2 += 8)
      WT[(size_t)(bn + ty + i2) * E_ + bk + tx] = f2bf(tile[tx][ty + i2]);
  }
}

// ------- 128x128 bf16 MFMA GEMM, BK=64, XOR-swizzled LDS, fused bias -------
// MODE 0: f32 out, ldc = N.
// MODE 1: qkv split -> Q cols (<1024) pre-scaled by QSC, bf16 into Cbf;
//         K cols (1024..2047) bf16 into Cbf; V cols (>=2048) transposed
//         into Vt[bh][d][s].
template <int MODE>
__global__ __launch_bounds__(256) void gemm_bt_bias(
    const unsigned short* __restrict__ A,
    const unsigned short* __restrict__ BT,
    const float* __restrict__ bias,
    float* __restrict__ Cf,
    unsigned short* __restrict__ Cbf,
    unsigned short* __restrict__ Vt,
    int M, int N, int K) {
  __shared__ __align__(16) unsigned short As[128 * 64];
  __shared__ __align__(16) unsigned short Bs[128 * 64];
  const int t = threadIdx.x;
  const int lane = t & 63, w = t >> 6;
  const int wr = w >> 1, wc = w & 1;
  const int m0 = blockIdx.y * 128, n0 = blockIdx.x * 128;
  const int lrow = lane & 15, lkg = lane >> 4;   // frag row / k-granule
  const int srow = t >> 3;            // 0..31 (+32p)
  const int sc8  = (t & 7) * 8;       // granule base (elems)
  const int sgc  = sc8 ^ (((t >> 3) & 7) << 3);  // swizzled source col

  f32x4 acc[4][4];
  const f32x4 z = {0.f, 0.f, 0.f, 0.f};
  #pragma unroll
  for (int i = 0; i < 4; ++i)
    #pragma unroll
    for (int j = 0; j < 4; ++j) acc[i][j] = z;

  for (int k0 = 0; k0 < K; k0 += 64) {
    __syncthreads();
    #pragma unroll
    for (int p = 0; p < 4; ++p) {
      const int r = srow + 32 * p;
      gload16(A  + (size_t)(m0 + r) * K + k0 + sgc, &As[r * 64 + sc8]);
      gload16(BT + (size_t)(n0 + r) * K + k0 + sgc, &Bs[r * 64 + sc8]);
    }
    __syncthreads();

    short8 af[4][2], bf[4][2];
    #pragma unroll
    for (int m = 0; m < 4; ++m) {
      const int row = wr * 64 + m * 16 + lrow;
      const int base = row * 64, sw = (row & 7) << 3;
      af[m][0] = *(const short8*)&As[base + ((lkg * 8) ^ sw)];
      af[m][1] = *(const short8*)&As[base + ((32 + lkg * 8) ^ sw)];
    }
    #pragma unroll
    for (int n = 0; n < 4; ++n) {
      const int row = wc * 64 + n * 16 + lrow;
      const int base = row * 64, sw = (row & 7) << 3;
      bf[n][0] = *(const short8*)&Bs[base + ((lkg * 8) ^ sw)];
      bf[n][1] = *(const short8*)&Bs[base + ((32 + lkg * 8) ^ sw)];
    }
    #pragma unroll
    for (int m = 0; m < 4; ++m)
      #pragma unroll
      for (int n = 0; n < 4; ++n) {
        acc[m][n] = __builtin_amdgcn_mfma_f32_16x16x32_bf16(af[m][0], bf[n][0],
                                                            acc[m][n], 0, 0, 0);
        acc[m][n] = __builtin_amdgcn_mfma_f32_16x16x32_bf16(af[m][1], bf[n][1],
                                                            acc[m][n], 0, 0, 0);
      }
  }

  const int r0 = (lane >> 4) * 4, c0 = lane & 15;
  #pragma unroll
  for (int m = 0; m < 4; ++m) {
    #pragma unroll
    for (int n = 0; n < 4; ++n) {
      const int row = m0 + wr * 64 + m * 16 + r0;
      const int col = n0 + wc * 64 + n * 16 + c0;
      const float bv = bias[col];
      if (MODE == 0) {
        #pragma unroll
        for (int r = 0; r < 4; ++r)
          Cf[(size_t)(row + r) * N + col] = acc[m][n][r] + bv;
      } else {
        if (col < 2 * E_) {
          const float sc = (col < E_) ? QSC : 1.0f;  // uniform per 16-col block
          #pragma unroll
          for (int r = 0; r < 4; ++r)
            Cbf[(size_t)(row + r) * QKS + col] = f2bf((acc[m][n][r] + bv) * sc);
        } else {
          const int hd = col - 2 * E_;
          ushort4 o;
          o.x = f2bf(acc[m][n][0] + bv);
          o.y = f2bf(acc[m][n][1] + bv);
          o.z = f2bf(acc[m][n][2] + bv);
          o.w = f2bf(acc[m][n][3] + bv);
          *(ushort4*)&Vt[(((size_t)(row >> 11) * H_ + (hd >> 6)) * HD_ +
                          (hd & 63)) * (size_t)S_ + (row & 2047)] = o;
        }
      }
    }
  }
}

// ---------------- flash attention (causal), QBLK=64, KVBLK=64 ----------------
// Swapped-QK^T; scores in exp2 domain (Q pre-scaled by 0.125*log2e).
// Fixed-reference softmax (no running max) => linear in kv-range; qt 24..31
// split into two kv-chunks writing f32 partials, combined by attn_combine.
__global__ __launch_bounds__(256) void flash_attn(
    const unsigned short* __restrict__ qk,
    const unsigned short* __restrict__ Vt,
    unsigned short* __restrict__ aout,
    float* __restrict__ Opart,           // [256][2][64][64]
    float* __restrict__ Lpart) {         // [256][2][64]
  __shared__ __align__(16) unsigned short Ks[2][64 * 64];   // [k][d], swizzled
  __shared__ __align__(16) unsigned short Vs[2][64 * 64];   // [d][k], swizzled
  __shared__ __align__(16) unsigned short Ps[4][16 * 64];   // per-wave P[q][k]

  const int t = threadIdx.x, lane = t & 63, w = t >> 6;
  const int bh = blockIdx.x;
  const int yy = blockIdx.y;            // 0..39, dispatch order = work order
  int qt, lo, hi, part = 0;
  bool split = false;
  if (yy < 8) {                         // longest singles first: len 24..17
    qt = 23 - yy; lo = 0; hi = qt + 1;
  } else if (yy < 24) {                 // split chunks: len ~16..12
    const int idx = yy - 8;
    qt = 31 - (idx >> 1); part = idx & 1;
    const int mid = (qt + 2) >> 1;
    lo = part ? mid : 0; hi = part ? qt + 1 : mid;
    split = true;
  } else {                              // short singles: len 16..1
    qt = 39 - yy; lo = 0; hi = qt + 1;
  }
  const int b = bh >> 4, h = bh & 15;
  const int lq = lane & 15;
  const int g  = lane >> 4;
  const int lk8 = g * 8;
  const int swzq = (lq & 7) << 3;
  const size_t basebs = (size_t)b * S_;
  const f32x4 z = {0.f, 0.f, 0.f, 0.f};

  short8 qf[2];
  {
    const int qrow = qt * 64 + w * 16 + lq;
    const unsigned short* qp = qk + (basebs + qrow) * QKS + h * HD_;
    qf[0] = *(const short8*)(qp + lk8);
    qf[1] = *(const short8*)(qp + 32 + lk8);
  }

  float l_q = 0.f;
  f32x4 o_acc[4];
  #pragma unroll
  for (int n = 0; n < 4; ++n) o_acc[n] = z;

  const int sr = t >> 3, scc = (t & 7) * 8;
  const unsigned short* kp0 =
      qk + (basebs + sr) * QKS + E_ + h * HD_ + (scc ^ ((sr & 7) << 3));
  const unsigned short* kp1 = kp0 + 32 * QKS;
  const unsigned short* vp0 =
      Vt + ((size_t)bh * HD_ + sr) * S_ + (scc ^ ((sr & 7) << 3));
  const unsigned short* vp1 = vp0 + 32 * S_;

  auto stage = [&](int buf, int kt) {
    const size_t koff = (size_t)kt * 64 * QKS;
    const size_t voff = (size_t)kt * 64;
    gload16(kp0 + koff, &Ks[buf][t * 8]);
    gload16(kp1 + koff, &Ks[buf][t * 8 + 2048]);
    gload16(vp0 + voff, &Vs[buf][t * 8]);
    gload16(vp1 + voff, &Vs[buf][t * 8 + 2048]);
  };

  stage(0, lo);
  __syncthreads();
  int cur = 0;

  for (int kt = lo; kt < hi; ++kt) {
    if (kt + 1 < hi) stage(cur ^ 1, kt + 1);

    f32x4 st[4];
    __builtin_amdgcn_s_setprio(1);
    #pragma unroll
    for (int f = 0; f < 4; ++f) {
      const int rowb = (f * 16 + lq) * 64;
      short8 kf0 = *(const short8*)&Ks[cur][rowb + (lk8 ^ swzq)];
      short8 kf1 = *(const short8*)&Ks[cur][rowb + ((lk8 + 32) ^ swzq)];
      st[f] = __builtin_amdgcn_mfma_f32_16x16x32_bf16(kf0, qf[0], z, 0, 0, 0);
      st[f] = __builtin_amdgcn_mfma_f32_16x16x32_bf16(kf1, qf[1], st[f], 0, 0, 0);
    }
    __builtin_amdgcn_s_setprio(0);

    if (kt == qt) {
      const int qcol = w * 16 + lq;
      #pragma unroll
      for (int f = 0; f < 4; ++f)
        #pragma unroll
        for (int r = 0; r < 4; ++r)
          if (16 * f + 4 * g + r > qcol) st[f][r] = -1e30f;
    }

    unsigned pw[4][2];
    #pragma unroll
    for (int f = 0; f < 4; ++f) {
      float p0 = exp2_fast(st[f][0]);
      float p1 = exp2_fast(st[f][1]);
      float p2 = exp2_fast(st[f][2]);
      float p3 = exp2_fast(st[f][3]);
      l_q += (p0 + p1) + (p2 + p3);
      asm("v_cvt_pk_bf16_f32 %0, %1, %2" : "=v"(pw[f][0]) : "v"(p0), "v"(p1));
      asm("v_cvt_pk_bf16_f32 %0, %1, %2" : "=v"(pw[f][1]) : "v"(p2), "v"(p3));
    }

    {
      unsigned short* pr = &Ps[w][lq * 64];
      #pragma unroll
      for (int f = 0; f < 4; ++f) {
        *(unsigned*)&pr[(16 * f + 4 * g) ^ swzq]       = pw[f][0];
        *(unsigned*)&pr[((16 * f + 4 * g + 2) ^ swzq)] = pw[f][1];
      }
    }

    short8 pa0 = *(const short8*)&Ps[w][lq * 64 + (lk8 ^ swzq)];
    short8 pa1 = *(const short8*)&Ps[w][lq * 64 + ((lk8 + 32) ^ swzq)];
    __builtin_amdgcn_s_setprio(1);
    #pragma unroll
    for (int n = 0; n < 4; ++n) {
      const int rowb = (n * 16 + lq) * 64;
      short8 vb0 = *(const short8*)&Vs[cur][rowb + (lk8 ^ swzq)];
      short8 vb1 = *(const short8*)&Vs[cur][rowb + ((lk8 + 32) ^ swzq)];
      o_acc[n] = __builtin_amdgcn_mfma_f32_16x16x32_bf16(pa0, vb0, o_acc[n], 0, 0, 0);
      o_acc[n] = __builtin_amdgcn_mfma_f32_16x16x32_bf16(pa1, vb1, o_acc[n], 0, 0, 0);
    }
    __builtin_amdgcn_s_setprio(0);

    __syncthreads();
    cur ^= 1;
  }

  l_q += __shfl_xor(l_q, 16);
  l_q += __shfl_xor(l_q, 32);

  if (!split) {
    const int qbase = qt * 64 + w * 16 + 4 * g;
    #pragma unroll
    for (int r = 0; r < 4; ++r) {
      const float lr = __shfl(l_q, 4 * g + r);
      const float inv = 1.0f / lr;
      const int row = qbase + r;
      #pragma unroll
      for (int n = 0; n < 4; ++n)
        aout[(basebs + row) * E_ + h * HD_ + n * 16 + lq] =
            f2bf(o_acc[n][r] * inv);
    }
  } else {
    const int sidx = (bh << 3) | (qt - 24);
    float* Ob = Opart + ((size_t)(sidx * 2 + part) << 12);  // 64*64
    #pragma unroll
    for (int r = 0; r < 4; ++r) {
      const int qrow = w * 16 + 4 * g + r;
      #pragma unroll
      for (int n = 0; n < 4; ++n)
        Ob[qrow * 64 + n * 16 + lq] = o_acc[n][r];
    }
    if (g == 0)
      Lpart[(sidx * 2 + part) * 64 + w * 16 + lq] = l_q;
  }
}

// ---------------- combine partials for split row-blocks ----------------
__global__ __launch_bounds__(256) void attn_combine(
    const float* __restrict__ Opart, const float* __restrict__ Lpart,
    unsigned short* __restrict__ aout) {
  const int s = blockIdx.x;            // 0..255
  const int bh = s >> 3, qt = 24 + (s & 7);
  const int b = bh >> 4, h = bh & 15;
  const int t = threadIdx.x;
  const int q = t >> 2;                // 0..63
  const int d0 = (t & 3) * 16;
  const float l = Lpart[(s * 2 + 0) * 64 + q] + Lpart[(s * 2 + 1) * 64 + q];
  const float inv = 1.0f / l;
  const float* p0 = Opart + ((size_t)(s * 2 + 0) << 12) + q * 64 + d0;
  const float* p1 = Opart + ((size_t)(s * 2 + 1) << 12) + q * 64 + d0;
  unsigned short* dst =
      aout + ((size_t)b * S_ + qt * 64 + q) * E_ + h * HD_ + d0;
  #pragma unroll
  for (int i = 0; i < 16; ++i)
    dst[i] = f2bf((p0[i] + p1[i]) * inv);
}

extern "C" void kernel_launch(void* const* d_in, const int* in_sizes, int n_in,
                              void* d_out, int out_size, void* d_ws, size_t ws_size,
                              hipStream_t stream) {
  const float* X  = (const float*)d_in[0];
  const float* Wa = (const float*)d_in[1];
  const float* ba = (const float*)d_in[2];
  const float* Wp = (const float*)d_in[3];
  const float* bp = (const float*)d_in[4];
  float* out = (float*)d_out;

  char* ws = (char*)d_ws;
  unsigned short* Xb  = (unsigned short*)ws; ws += (size_t)M_ * E_ * 2;    // 8 MB
  unsigned short* WaT = (unsigned short*)ws; ws += (size_t)E3_ * E_ * 2;   // 6 MB
  unsigned short* WpT = (unsigned short*)ws; ws += (size_t)E_ * E_ * 2;    // 2 MB
  unsigned short* QK  = (unsigned short*)ws; ws += (size_t)M_ * QKS * 2;   // 16 MB
  unsigned short* Vt  = (unsigned short*)ws; ws += (size_t)M_ * E_ * 2;    // 8 MB
  unsigned short* AO  = (unsigned short*)ws; ws += (size_t)M_ * E_ * 2;    // 8 MB
  float* Opart = (float*)ws; ws += (size_t)256 * 2 * 64 * 64 * 4;          // 8 MB
  float* Lpart = (float*)ws; ws += (size_t)256 * 2 * 64 * 4;               // 128 KB

  prep<<<8192, 256, 0, stream>>>(X, Wa, Wp, Xb, WaT, WpT);
  gemm_bt_bias<1><<<dim3(E3_ / 128, M_ / 128), 256, 0, stream>>>(
      Xb, WaT, ba, nullptr, QK, Vt, M_, E3_, E_);
  flash_attn<<<dim3(B_ * H_, 40), 256, 0, stream>>>(QK, Vt, AO, Opart, Lpart);
  attn_combine<<<256, 256, 0, stream>>>(Opart, Lpart, AO);
  gemm_bt_bias<0><<<dim3(E_ / 128, M_ / 128), 256, 0, stream>>>(
      AO, WpT, bp, out, nullptr, nullptr, M_, E_, E_);
}

// Round 13
// 104.416 us; speedup vs baseline: 1.2156x; 1.0184x over previous
//
#include <hip/hip_runtime.h>
#include <hip/hip_bf16.h>

#define B_   2
#define S_   2048
#define E_   1024
#define H_   16
#define HD_  64
#define E3_  3072
#define M_   4096   // B*S
#define QKS  2048   // stride of QK buffer
#define QSC  0.1803368801111f   // 0.125 * log2(e): Q pre-scale, exp2 domain

using short8 = __attribute__((ext_vector_type(8))) short;
using f32x4  = __attribute__((ext_vector_type(4))) float;

__device__ __forceinline__ unsigned short f2bf(float f) {
  union { float f; unsigned v; } t; t.f = f;
  unsigned r = t.v + 0x7FFFu + ((t.v >> 16) & 1u);  // RNE
  return (unsigned short)(r >> 16);
}

__device__ __forceinline__ float exp2_fast(float x) {
  float r;
  asm("v_exp_f32 %0, %1" : "=v"(r) : "v"(x));
  return r;
}

__device__ __forceinline__ void gload16(const void* g, void* l) {
  __builtin_amdgcn_global_load_lds(
      (const __attribute__((address_space(1))) unsigned int*)g,
      (__attribute__((address_space(3))) unsigned int*)l, 16, 0, 0);
}

// ---- prep: X f32->bf16 + both weight transposes, one launch ----
// blocks [0,4096): cvt X; [4096,7168): transpose Wa; [7168,8192): transpose Wp
__global__ __launch_bounds__(256) void prep(
    const float* __restrict__ X, const float* __restrict__ Wa,
    const float* __restrict__ Wp,
    unsigned short* __restrict__ Xb, unsigned short* __restrict__ WaT,
    unsigned short* __restrict__ WpT) {
  __shared__ float tile[32][33];
  const int id = blockIdx.x;
  if (id < 4096) {
    const int i = (id * 256 + threadIdx.x) * 4;
    float4 v = *(const float4*)(X + i);
    ushort4 o;
    o.x = f2bf(v.x); o.y = f2bf(v.y); o.z = f2bf(v.z); o.w = f2bf(v.w);
    *(ushort4*)(Xb + i) = o;
  } else {
    const float* W; unsigned short* WT; int N, bn, bk;
    if (id < 7168) {
      W = Wa; WT = WaT; N = E3_;
      const int j = id - 4096; bn = (j % 96) * 32; bk = (j / 96) * 32;
    } else {
      W = Wp; WT = WpT; N = E_;
      const int j = id - 7168; bn = (j & 31) * 32; bk = (j >> 5) * 32;
    }
    const int tx = threadIdx.x & 31, ty = threadIdx.x >> 5;  // 32 x 8
    #pragma unroll
    for (int i2 = 0; i2 < 32; i2 += 8)
      tile[ty + i2][tx] = W[(size_t)(bk + ty + i2) * N + bn + tx];
    __syncthreads();
    #pragma unroll
    for (int i2 = 0; i2 < 32; i2 += 8)
      WT[(size_t)(bn + ty + i2) * E_ + bk + tx] = f2bf(tile[tx][ty + i2]);
  }
}

// ------- 128x128 bf16 MFMA GEMM, BK=64, XOR-swizzled LDS, fused bias -------
// MODE 0: f32 out, ldc = N.
// MODE 1: qkv split -> Q cols (<1024) pre-scaled by QSC, bf16 into Cbf;
//         K cols (1024..2047) bf16 into Cbf; V cols (>=2048) transposed
//         into Vt[bh][d][s].
template <int MODE>
__global__ __launch_bounds__(256) void gemm_bt_bias(
    const unsigned short* __restrict__ A,
    const unsigned short* __restrict__ BT,
    const float* __restrict__ bias,
    float* __restrict__ Cf,
    unsigned short* __restrict__ Cbf,
    unsigned short* __restrict__ Vt,
    int M, int N, int K) {
  __shared__ __align__(16) unsigned short As[128 * 64];
  __shared__ __align__(16) unsigned short Bs[128 * 64];
  const int t = threadIdx.x;
  const int lane = t & 63, w = t >> 6;
  const int wr = w >> 1, wc = w & 1;
  const int m0 = blockIdx.y * 128, n0 = blockIdx.x * 128;
  const int lrow = lane & 15, lkg = lane >> 4;   // frag row / k-granule
  const int srow = t >> 3;            // 0..31 (+32p)
  const int sc8  = (t & 7) * 8;       // granule base (elems)
  const int sgc  = sc8 ^ (((t >> 3) & 7) << 3);  // swizzled source col

  f32x4 acc[4][4];
  const f32x4 z = {0.f, 0.f, 0.f, 0.f};
  #pragma unroll
  for (int i = 0; i < 4; ++i)
    #pragma unroll
    for (int j = 0; j < 4; ++j) acc[i][j] = z;

  for (int k0 = 0; k0 < K; k0 += 64) {
    __syncthreads();
    #pragma unroll
    for (int p = 0; p < 4; ++p) {
      const int r = srow + 32 * p;
      gload16(A  + (size_t)(m0 + r) * K + k0 + sgc, &As[r * 64 + sc8]);
      gload16(BT + (size_t)(n0 + r) * K + k0 + sgc, &Bs[r * 64 + sc8]);
    }
    __syncthreads();

    short8 af[4][2], bf[4][2];
    #pragma unroll
    for (int m = 0; m < 4; ++m) {
      const int row = wr * 64 + m * 16 + lrow;
      const int base = row * 64, sw = (row & 7) << 3;
      af[m][0] = *(const short8*)&As[base + ((lkg * 8) ^ sw)];
      af[m][1] = *(const short8*)&As[base + ((32 + lkg * 8) ^ sw)];
    }
    #pragma unroll
    for (int n = 0; n < 4; ++n) {
      const int row = wc * 64 + n * 16 + lrow;
      const int base = row * 64, sw = (row & 7) << 3;
      bf[n][0] = *(const short8*)&Bs[base + ((lkg * 8) ^ sw)];
      bf[n][1] = *(const short8*)&Bs[base + ((32 + lkg * 8) ^ sw)];
    }
    #pragma unroll
    for (int m = 0; m < 4; ++m)
      #pragma unroll
      for (int n = 0; n < 4; ++n) {
        acc[m][n] = __builtin_amdgcn_mfma_f32_16x16x32_bf16(af[m][0], bf[n][0],
                                                            acc[m][n], 0, 0, 0);
        acc[m][n] = __builtin_amdgcn_mfma_f32_16x16x32_bf16(af[m][1], bf[n][1],
                                                            acc[m][n], 0, 0, 0);
      }
  }

  const int r0 = (lane >> 4) * 4, c0 = lane & 15;
  #pragma unroll
  for (int m = 0; m < 4; ++m) {
    #pragma unroll
    for (int n = 0; n < 4; ++n) {
      const int row = m0 + wr * 64 + m * 16 + r0;
      const int col = n0 + wc * 64 + n * 16 + c0;
      const float bv = bias[col];
      if (MODE == 0) {
        #pragma unroll
        for (int r = 0; r < 4; ++r)
          Cf[(size_t)(row + r) * N + col] = acc[m][n][r] + bv;
      } else {
        if (col < 2 * E_) {
          const float sc = (col < E_) ? QSC : 1.0f;  // uniform per 16-col block
          #pragma unroll
          for (int r = 0; r < 4; ++r)
            Cbf[(size_t)(row + r) * QKS + col] = f2bf((acc[m][n][r] + bv) * sc);
        } else {
          const int hd = col - 2 * E_;
          ushort4 o;
          o.x = f2bf(acc[m][n][0] + bv);
          o.y = f2bf(acc[m][n][1] + bv);
          o.z = f2bf(acc[m][n][2] + bv);
          o.w = f2bf(acc[m][n][3] + bv);
          *(ushort4*)&Vt[(((size_t)(row >> 11) * H_ + (hd >> 6)) * HD_ +
                          (hd & 63)) * (size_t)S_ + (row & 2047)] = o;
        }
      }
    }
  }
}

// ---------------- flash attention (causal), QBLK=64, KVBLK=64 ----------------
// Swapped-QK^T; scores in exp2 domain (Q pre-scaled by 0.125*log2e).
// Fixed-reference softmax (no running max) => linear in kv-range; qt 24..31
// split into two kv-chunks writing f32 partials, combined by attn_combine.
// P redistribution (S^T lane layout -> PV A-fragment) done fully in-register
// with v_permlane32_swap + v_permlane16_swap: chain (A,B) ->
// A''=[A(0),A(2),B(0),B(2)], B''=[A(1),A(3),B(1),B(3)] (indexed by g).
__global__ __launch_bounds__(256) void flash_attn(
    const unsigned short* __restrict__ qk,
    const unsigned short* __restrict__ Vt,
    unsigned short* __restrict__ aout,
    float* __restrict__ Opart,           // [256][2][64][64]
    float* __restrict__ Lpart) {         // [256][2][64]
  __shared__ __align__(16) unsigned short Ks[2][64 * 64];   // [k][d], swizzled
  __shared__ __align__(16) unsigned short Vs[2][64 * 64];   // [d][k], swizzled

  const int t = threadIdx.x, lane = t & 63, w = t >> 6;
  const int bh = blockIdx.x;
  const int yy = blockIdx.y;            // 0..39, dispatch order = work order
  int qt, lo, hi, part = 0;
  bool split = false;
  if (yy < 8) {                         // longest singles first: len 24..17
    qt = 23 - yy; lo = 0; hi = qt + 1;
  } else if (yy < 24) {                 // split chunks: len ~16..12
    const int idx = yy - 8;
    qt = 31 - (idx >> 1); part = idx & 1;
    const int mid = (qt + 2) >> 1;
    lo = part ? mid : 0; hi = part ? qt + 1 : mid;
    split = true;
  } else {                              // short singles: len 16..1
    qt = 39 - yy; lo = 0; hi = qt + 1;
  }
  const int b = bh >> 4, h = bh & 15;
  const int lq = lane & 15;
  const int g  = lane >> 4;
  const int lk8 = g * 8;
  const int swzq = (lq & 7) << 3;
  const size_t basebs = (size_t)b * S_;
  const f32x4 z = {0.f, 0.f, 0.f, 0.f};

  short8 qf[2];
  {
    const int qrow = qt * 64 + w * 16 + lq;
    const unsigned short* qp = qk + (basebs + qrow) * QKS + h * HD_;
    qf[0] = *(const short8*)(qp + lk8);
    qf[1] = *(const short8*)(qp + 32 + lk8);
  }

  float l_q = 0.f;
  f32x4 o_acc[4];
  #pragma unroll
  for (int n = 0; n < 4; ++n) o_acc[n] = z;

  const int sr = t >> 3, scc = (t & 7) * 8;
  const unsigned short* kp0 =
      qk + (basebs + sr) * QKS + E_ + h * HD_ + (scc ^ ((sr & 7) << 3));
  const unsigned short* kp1 = kp0 + 32 * QKS;
  const unsigned short* vp0 =
      Vt + ((size_t)bh * HD_ + sr) * S_ + (scc ^ ((sr & 7) << 3));
  const unsigned short* vp1 = vp0 + 32 * S_;

  auto stage = [&](int buf, int kt) {
    const size_t koff = (size_t)kt * 64 * QKS;
    const size_t voff = (size_t)kt * 64;
    gload16(kp0 + koff, &Ks[buf][t * 8]);
    gload16(kp1 + koff, &Ks[buf][t * 8 + 2048]);
    gload16(vp0 + voff, &Vs[buf][t * 8]);
    gload16(vp1 + voff, &Vs[buf][t * 8 + 2048]);
  };

  stage(0, lo);
  __syncthreads();
  int cur = 0;

  for (int kt = lo; kt < hi; ++kt) {
    if (kt + 1 < hi) stage(cur ^ 1, kt + 1);

    f32x4 st[4];
    __builtin_amdgcn_s_setprio(1);
    #pragma unroll
    for (int f = 0; f < 4; ++f) {
      const int rowb = (f * 16 + lq) * 64;
      short8 kf0 = *(const short8*)&Ks[cur][rowb + (lk8 ^ swzq)];
      short8 kf1 = *(const short8*)&Ks[cur][rowb + ((lk8 + 32) ^ swzq)];
      st[f] = __builtin_amdgcn_mfma_f32_16x16x32_bf16(kf0, qf[0], z, 0, 0, 0);
      st[f] = __builtin_amdgcn_mfma_f32_16x16x32_bf16(kf1, qf[1], st[f], 0, 0, 0);
    }
    __builtin_amdgcn_s_setprio(0);

    if (kt == qt) {
      const int qcol = w * 16 + lq;
      #pragma unroll
      for (int f = 0; f < 4; ++f)
        #pragma unroll
        for (int r = 0; r < 4; ++r)
          if (16 * f + 4 * g + r > qcol) st[f][r] = -1e30f;
    }

    // P = exp2(S), packed bf16 pairs, per-lane partial l
    unsigned pw[4][2];
    #pragma unroll
    for (int f = 0; f < 4; ++f) {
      float p0 = exp2_fast(st[f][0]);
      float p1 = exp2_fast(st[f][1]);
      float p2 = exp2_fast(st[f][2]);
      float p3 = exp2_fast(st[f][3]);
      l_q += (p0 + p1) + (p2 + p3);
      asm("v_cvt_pk_bf16_f32 %0, %1, %2" : "=v"(pw[f][0]) : "v"(p0), "v"(p1));
      asm("v_cvt_pk_bf16_f32 %0, %1, %2" : "=v"(pw[f][1]) : "v"(p2), "v"(p3));
    }

    // in-register P redistribution: 4 chains x (permlane32_swap+permlane16_swap)
    unsigned c1a = pw[0][0], c1b = pw[1][0];
    unsigned c2a = pw[0][1], c2b = pw[1][1];
    unsigned c3a = pw[2][0], c3b = pw[3][0];
    unsigned c4a = pw[2][1], c4b = pw[3][1];
    asm("v_permlane32_swap_b32 %0, %1" : "+v"(c1a), "+v"(c1b));
    asm("v_permlane16_swap_b32 %0, %1" : "+v"(c1a), "+v"(c1b));
    asm("v_permlane32_swap_b32 %0, %1" : "+v"(c2a), "+v"(c2b));
    asm("v_permlane16_swap_b32 %0, %1" : "+v"(c2a), "+v"(c2b));
    asm("v_permlane32_swap_b32 %0, %1" : "+v"(c3a), "+v"(c3b));
    asm("v_permlane16_swap_b32 %0, %1" : "+v"(c3a), "+v"(c3b));
    asm("v_permlane32_swap_b32 %0, %1" : "+v"(c4a), "+v"(c4b));
    asm("v_permlane16_swap_b32 %0, %1" : "+v"(c4a), "+v"(c4b));
    union U8 { unsigned u[4]; short8 s; };
    U8 pa0u = {{c1a, c2a, c1b, c2b}};
    U8 pa1u = {{c3a, c4a, c3b, c4b}};
    const short8 pa0 = pa0u.s, pa1 = pa1u.s;

    __builtin_amdgcn_s_setprio(1);
    #pragma unroll
    for (int n = 0; n < 4; ++n) {
      const int rowb = (n * 16 + lq) * 64;
      short8 vb0 = *(const short8*)&Vs[cur][rowb + (lk8 ^ swzq)];
      short8 vb1 = *(const short8*)&Vs[cur][rowb + ((lk8 + 32) ^ swzq)];
      o_acc[n] = __builtin_amdgcn_mfma_f32_16x16x32_bf16(pa0, vb0, o_acc[n], 0, 0, 0);
      o_acc[n] = __builtin_amdgcn_mfma_f32_16x16x32_bf16(pa1, vb1, o_acc[n], 0, 0, 0);
    }
    __builtin_amdgcn_s_setprio(0);

    __syncthreads();
    cur ^= 1;
  }

  l_q += __shfl_xor(l_q, 16);
  l_q += __shfl_xor(l_q, 32);

  if (!split) {
    const int qbase = qt * 64 + w * 16 + 4 * g;
    #pragma unroll
    for (int r = 0; r < 4; ++r) {
      const float lr = __shfl(l_q, 4 * g + r);
      const float inv = 1.0f / lr;
      const int row = qbase + r;
      #pragma unroll
      for (int n = 0; n < 4; ++n)
        aout[(basebs + row) * E_ + h * HD_ + n * 16 + lq] =
            f2bf(o_acc[n][r] * inv);
    }
  } else {
    const int sidx = (bh << 3) | (qt - 24);
    float* Ob = Opart + ((size_t)(sidx * 2 + part) << 12);  // 64*64
    #pragma unroll
    for (int r = 0; r < 4; ++r) {
      const int qrow = w * 16 + 4 * g + r;
      #pragma unroll
      for (int n = 0; n < 4; ++n)
        Ob[qrow * 64 + n * 16 + lq] = o_acc[n][r];
    }
    if (g == 0)
      Lpart[(sidx * 2 + part) * 64 + w * 16 + lq] = l_q;
  }
}

// ---------------- combine partials for split row-blocks ----------------
__global__ __launch_bounds__(256) void attn_combine(
    const float* __restrict__ Opart, const float* __restrict__ Lpart,
    unsigned short* __restrict__ aout) {
  const int s = blockIdx.x;            // 0..255
  const int bh = s >> 3, qt = 24 + (s & 7);
  const int b = bh >> 4, h = bh & 15;
  const int t = threadIdx.x;
  const int q = t >> 2;                // 0..63
  const int d0 = (t & 3) * 16;
  const float l = Lpart[(s * 2 + 0) * 64 + q] + Lpart[(s * 2 + 1) * 64 + q];
  const float inv = 1.0f / l;
  const float* p0 = Opart + ((size_t)(s * 2 + 0) << 12) + q * 64 + d0;
  const float* p1 = Opart + ((size_t)(s * 2 + 1) << 12) + q * 64 + d0;
  unsigned short* dst =
      aout + ((size_t)b * S_ + qt * 64 + q) * E_ + h * HD_ + d0;
  #pragma unroll
  for (int i = 0; i < 16; ++i)
    dst[i] = f2bf((p0[i] + p1[i]) * inv);
}

extern "C" void kernel_launch(void* const* d_in, const int* in_sizes, int n_in,
                              void* d_out, int out_size, void* d_ws, size_t ws_size,
                              hipStream_t stream) {
  const float* X  = (const float*)d_in[0];
  const float* Wa = (const float*)d_in[1];
  const float* ba = (const float*)d_in[2];
  const float* Wp = (const float*)d_in[3];
  const float* bp = (const float*)d_in[4];
  float* out = (float*)d_out;

  char* ws = (char*)d_ws;
  unsigned short* Xb  = (unsigned short*)ws; ws += (size_t)M_ * E_ * 2;    // 8 MB
  unsigned short* WaT = (unsigned short*)ws; ws += (size_t)E3_ * E_ * 2;   // 6 MB
  unsigned short* WpT = (unsigned short*)ws; ws += (size_t)E_ * E_ * 2;    // 2 MB
  unsigned short* QK  = (unsigned short*)ws; ws += (size_t)M_ * QKS * 2;   // 16 MB
  unsigned short* Vt  = (unsigned short*)ws; ws += (size_t)M_ * E_ * 2;    // 8 MB
  unsigned short* AO  = (unsigned short*)ws; ws += (size_t)M_ * E_ * 2;    // 8 MB
  float* Opart = (float*)ws; ws += (size_t)256 * 2 * 64 * 64 * 4;          // 8 MB
  float* Lpart = (float*)ws; ws += (size_t)256 * 2 * 64 * 4;               // 128 KB

  prep<<<8192, 256, 0, stream>>>(X, Wa, Wp, Xb, WaT, WpT);
  gemm_bt_bias<1><<<dim3(E3_ / 128, M_ / 128), 256, 0, stream>>>(
      Xb, WaT, ba, nullptr, QK, Vt, M_, E3_, E_);
  flash_attn<<<dim3(B_ * H_, 40), 256, 0, stream>>>(QK, Vt, AO, Opart, Lpart);
  attn_combine<<<256, 256, 0, stream>>>(Opart, Lpart, AO);
  gemm_bt_bias<0><<<dim3(E_ / 128, M_ / 128), 256, 0, stream>>>(
      AO, WpT, bp, out, nullptr, nullptr, M_, E_, E_);
}